// Round 5
// baseline (354.799 us; speedup 1.0000x reference)
//
#include <hip/hip_runtime.h>
#include <math.h>

// Problem shapes
constexpr int B = 4, H = 16, S = 1024, D = 256, P = 64;
constexpr long long N_ROWS = (long long)B * H * S;            // 65536
// Output segment offsets (floats, concatenated in return order)
constexpr long long OFF_RT = 0;                               // routing_scores
constexpr long long SZ_RT  = N_ROWS;                          // 65536
constexpr long long OFF_OR = OFF_RT + SZ_RT;                  // optimal_routes
constexpr long long SZ_OR  = N_ROWS * (long long)S;           // 67108864
constexpr long long OFF_TW = OFF_OR + SZ_OR;                  // transfer_weights
constexpr long long SZ_TW  = 16LL * 64 * 64;                  // 65536
constexpr long long OFF_PS = OFF_TW + SZ_TW;                  // pattern_scores

typedef _Float16 half8   __attribute__((ext_vector_type(8)));
typedef _Float16 half4v  __attribute__((ext_vector_type(4)));
typedef float    floatx4 __attribute__((ext_vector_type(4)));   // clang vector:
// OK for __builtin_nontemporal_* (HIP's float4 struct is NOT — R3 compile fail)

// ---------------------------------------------------------------------------
// Kernel 1: normalize patterns, fold in 1/TEMPERATURE = 10, split into f16
// hi/lo (a = hi + lo) for split-precision MFMA. Layout [p][k] row-major.
__global__ __launch_bounds__(64) void k_normalize(const float* __restrict__ pat,
                                                  _Float16* __restrict__ pnh,
                                                  _Float16* __restrict__ pnl) {
    int p    = blockIdx.x;
    int lane = threadIdx.x;                 // 0..63, covers 256 floats as floatx4
    const floatx4* src = (const floatx4*)(pat + (long long)p * D);
    floatx4 v = src[lane];
    float ss = v.x * v.x + v.y * v.y + v.z * v.z + v.w * v.w;
    #pragma unroll
    for (int m = 1; m < 64; m <<= 1) ss += __shfl_xor(ss, m, 64);
    float scale = 10.0f / fmaxf(sqrtf(ss), 1e-12f);
    float a[4] = { v.x * scale, v.y * scale, v.z * scale, v.w * scale };
    half4v hh, ll;
    #pragma unroll
    for (int j = 0; j < 4; ++j) {
        _Float16 h = (_Float16)a[j];
        hh[j] = h;
        ll[j] = (_Float16)(a[j] - (float)h);
    }
    *(half4v*)(pnh + (long long)p * D + lane * 4) = hh;
    *(half4v*)(pnl + (long long)p * D + lane * 4) = ll;
}

// ---------------------------------------------------------------------------
// Kernel 2 (fused): per block of 64 state rows --
//   (a) routing_scores slice (constant 1/1024) + transfer_weights slice copy
//   (b) optimal_routes tile: 64 rows x 4 KB, value depends only on column ->
//       one floatx4 per thread stored 64x, non-temporal (streaming, no reuse)
//   (c) sims = states @ pn^T via f16 split-precision MFMA + row softmax.
// Fusion rationale: routes (256 MB W) and gemm (64 MB R + 16 MB W) are both
// HBM-bound; serialized they cost 45+25 us, fused the HBM pipe sees one
// 336 MB stream ~= 52 us at the fills' demonstrated 6.5 TB/s.
__global__ __launch_bounds__(256) void k_fused(
        const float* __restrict__ states,
        const _Float16* __restrict__ pnh,
        const _Float16* __restrict__ pnl,
        const float* __restrict__ tw,
        float* __restrict__ out) {
    const int  t   = threadIdx.x;
    const long long blk = blockIdx.x;

    // --- (a) small segments: 64 elements of each per block -----------------
    if (t < 64) {
        out[OFF_RT + blk * 64 + t] = 0.0009765625f;            // 1/1024
        out[OFF_TW + blk * 64 + t] = tw[blk * 64 + t];
    }

    // --- (b) optimal_routes tile: rows blk*64 .. +63 -----------------------
    {
        float b0 = (float)(t * 4) * (-0.0009765625f);
        floatx4 v;
        v.x = b0;
        v.y = b0 - 0.0009765625f;
        v.z = b0 - 0.001953125f;
        v.w = b0 - 0.0029296875f;
        floatx4* dst = (floatx4*)(out + OFF_OR + blk * 64 * (long long)S) + t;
        #pragma unroll 8
        for (int i = 0; i < 64; ++i) {
            __builtin_nontemporal_store(v, dst + i * 256);     // row i, col 4t
        }
    }

    // --- (c) GEMM + softmax ------------------------------------------------
    int wave = t >> 6;
    int lane = t & 63;
    int q    = lane >> 4;                  // quad 0..3
    int m    = lane & 15;
    long long row0 = blk * 64 + wave * 16;
    const float* __restrict__ arow = states + (row0 + m) * D + q * 8;

    floatx4 acc[4] = {floatx4{0,0,0,0}, floatx4{0,0,0,0},
                      floatx4{0,0,0,0}, floatx4{0,0,0,0}};

    #pragma unroll 2
    for (int kk = 0; kk < 8; ++kk) {
        floatx4 a0 = __builtin_nontemporal_load((const floatx4*)(arow + kk * 32));
        floatx4 a1 = __builtin_nontemporal_load((const floatx4*)(arow + kk * 32 + 4));
        float av[8] = { a0.x, a0.y, a0.z, a0.w, a1.x, a1.y, a1.z, a1.w };
        half8 ah, al;
        #pragma unroll
        for (int j = 0; j < 8; ++j) {
            _Float16 h = (_Float16)av[j];
            ah[j] = h;
            al[j] = (_Float16)(av[j] - (float)h);
        }
        #pragma unroll
        for (int tt = 0; tt < 4; ++tt) {
            long long boff = (long long)(tt * 16 + m) * D + kk * 32 + q * 8;
            half8 bh = *(const half8*)(pnh + boff);
            half8 bl = *(const half8*)(pnl + boff);
            acc[tt] = __builtin_amdgcn_mfma_f32_16x16x32_f16(ah, bh, acc[tt], 0, 0, 0);
            acc[tt] = __builtin_amdgcn_mfma_f32_16x16x32_f16(al, bh, acc[tt], 0, 0, 0);
            acc[tt] = __builtin_amdgcn_mfma_f32_16x16x32_f16(ah, bl, acc[tt], 0, 0, 0);
        }
    }

    // Row softmax: row = q*4 + r lives in the 16 lanes sharing q (shuffle
    // masks 1..8 stay inside the group); each lane holds 4 cols (one per tile).
    float e[4][4];
    #pragma unroll
    for (int r = 0; r < 4; ++r) {
        float mx = fmaxf(fmaxf(acc[0][r], acc[1][r]), fmaxf(acc[2][r], acc[3][r]));
        #pragma unroll
        for (int msk = 1; msk < 16; msk <<= 1) mx = fmaxf(mx, __shfl_xor(mx, msk, 64));
        float s = 0.0f;
        #pragma unroll
        for (int tt = 0; tt < 4; ++tt) { e[tt][r] = __expf(acc[tt][r] - mx); s += e[tt][r]; }
        #pragma unroll
        for (int msk = 1; msk < 16; msk <<= 1) s += __shfl_xor(s, msk, 64);
        float inv = 1.0f / s;
        long long row = row0 + q * 4 + r;
        #pragma unroll
        for (int tt = 0; tt < 4; ++tt) {
            out[OFF_PS + row * P + tt * 16 + m] = e[tt][r] * inv;
        }
    }
}

// ---------------------------------------------------------------------------
extern "C" void kernel_launch(void* const* d_in, const int* in_sizes, int n_in,
                              void* d_out, int out_size, void* d_ws, size_t ws_size,
                              hipStream_t stream) {
    const float* states   = (const float*)d_in[0];   // (4,16,1024,256) fp32
    const float* patterns = (const float*)d_in[1];   // (64,256) fp32
    const float* transfer = (const float*)d_in[2];   // (16,64,64) fp32
    float* out = (float*)d_out;
    _Float16* pnh = (_Float16*)d_ws;                 // 64*256 halves = 32 KB
    _Float16* pnl = pnh + P * D;                     // +32 KB

    k_normalize<<<dim3(P), dim3(64), 0, stream>>>(patterns, pnh, pnl);

    k_fused<<<dim3(1024), dim3(256), 0, stream>>>(states, pnh, pnl, transfer, out);
}